// Round 1
// baseline (728.363 us; speedup 1.0000x reference)
//
#include <hip/hip_runtime.h>
#include <cmath>

// PREFFFT: masked-spectrum iFFT2 (3 planes x 128ch x 256x256) + bilinear
// grid-sample at 262144 points + 8-term Fourier integration -> (N,16).
//
// Derivation of the gather weights:
//   out[n][c] = sum_r cos(th_r)*feat[8c+r] - sin(th_r)*feat[128+8c+r],
//   th_r = 2*pi*s*(2^r-1)/256,  s = (icoord+1)*127.5
// feat[k] = (k even ? Re : Im) of iFFT2 plane-channel k>>1, stored
// channel-last: feat[y][x][k] (256 floats = 1KB per pixel).

__device__ __forceinline__ int brev8(int x) { return (int)(__brev((unsigned)x) >> 24); }

// ---------------- Pass 1: iFFT over y for each (ch, x<128) column ----------
// input  P[ch][y][x][2]   (only y<128, x<128 survive the mask), scale 1/65536
// output X[ch][v][x]      complex, v in [0,256), x in [0,128)
__global__ __launch_bounds__(256) void pass1_kernel(const float* __restrict__ P,
                                                    float2* __restrict__ X) {
    __shared__ float2 tw[128];
    __shared__ float2 tile[256 * 17];   // [pos][col], stride 17 breaks bank conflicts

    int t = threadIdx.x;
    if (t < 128) {
        float s, c;
        sincospif((float)t * (1.0f / 128.0f), &s, &c);
        tw[t] = make_float2(c, s);      // e^{+2 pi i t/256} (inverse FFT)
    }
    int b  = blockIdx.x;
    int ch = b >> 3;                    // 0..127
    int x0 = (b & 7) << 4;              // 0..112 (only x<128 is nonzero)
    const float* src = P + (size_t)ch * 131072 + x0 * 2;

    const float scale = 1.0f / 65536.0f;   // 1/(256*256) ifft2 normalization
#pragma unroll
    for (int k = 0; k < 4; k++) {
        int i = t + (k << 8);           // 0..1023
        int y = i >> 3;                 // 0..127
        int j = i & 7;                  // float4 within the 16-complex row chunk
        float4 v = *(const float4*)(src + (size_t)y * 512 + (j << 2));
        float2 c0 = make_float2(v.x * scale, v.y * scale);
        float2 c1 = make_float2(v.z * scale, v.w * scale);
        int pos = brev8(y);             // even; writing pos and pos+1 folds stage 1
        tile[pos * 17 + 2 * j]           = c0;
        tile[(pos + 1) * 17 + 2 * j]     = c0;
        tile[pos * 17 + 2 * j + 1]       = c1;
        tile[(pos + 1) * 17 + 2 * j + 1] = c1;
    }
    __syncthreads();
    for (int s = 2; s <= 8; s++) {      // radix-2 DIT, stages m=4..256
        int half = 1 << (s - 1);
        int col = t & 15;
        int bb  = t >> 4;
#pragma unroll
        for (int k = 0; k < 8; k++) {
            int bf = bb + (k << 4);     // 0..127, butterflies partition indices
            int j  = bf & (half - 1);
            int g  = bf >> (s - 1);
            int i0 = (g << s) + j;
            int i1 = i0 + half;
            float2 u = tile[i0 * 17 + col];
            float2 v = tile[i1 * 17 + col];
            float2 w = tw[j << (8 - s)];
            float2 vt = make_float2(v.x * w.x - v.y * w.y, v.x * w.y + v.y * w.x);
            tile[i0 * 17 + col] = make_float2(u.x + vt.x, u.y + vt.y);
            tile[i1 * 17 + col] = make_float2(u.x - vt.x, u.y - vt.y);
        }
        __syncthreads();
    }
    float2* dst = X + (size_t)ch * 32768 + x0;
#pragma unroll
    for (int k = 0; k < 16; k++) {
        int i = t + (k << 8);           // 0..4095
        int v = i >> 4;
        int col = i & 15;
        dst[(size_t)v * 128 + col] = tile[v * 17 + col];
    }
}

// ---------------- Pass 2: iFFT over x for each (v, ch) row ------------------
// input  X[ch][v][x<128]; output feat[v][x][2*ch+part]
// 8 channels per block so the k-scatter writes are full 64B lines.
__global__ __launch_bounds__(512) void pass2_kernel(const float2* __restrict__ X,
                                                    float* __restrict__ feat) {
    __shared__ float2 tw[128];
    __shared__ float2 rows[8 * 257];    // one 256-pt line per wave, +1 pad

    int t = threadIdx.x;
    if (t < 128) {
        float s, c;
        sincospif((float)t * (1.0f / 128.0f), &s, &c);
        tw[t] = make_float2(c, s);
    }
    int w = t >> 6;
    int l = t & 63;
    int v   = blockIdx.x & 255;
    int ch0 = (blockIdx.x >> 8) << 3;
    int ch  = ch0 + w;

    const float4* src = (const float4*)(X + ((size_t)ch * 256 + v) * 128);
    float4 d = src[l];                  // complex x=2l and x=2l+1
    float2* row = rows + w * 257;
    int p0 = brev8(2 * l);
    int p1 = brev8(2 * l + 1);
    row[p0]     = make_float2(d.x, d.y);
    row[p0 + 1] = make_float2(d.x, d.y);
    row[p1]     = make_float2(d.z, d.w);
    row[p1 + 1] = make_float2(d.z, d.w);
    __syncthreads();
    for (int s = 2; s <= 8; s++) {
        int half = 1 << (s - 1);
#pragma unroll
        for (int k = 0; k < 2; k++) {
            int bf = l + (k << 6);
            int j  = bf & (half - 1);
            int g  = bf >> (s - 1);
            int i0 = (g << s) + j;
            int i1 = i0 + half;
            float2 u  = row[i0];
            float2 vv = row[i1];
            float2 wq = tw[j << (8 - s)];
            float2 vt = make_float2(vv.x * wq.x - vv.y * wq.y,
                                    vv.x * wq.y + vv.y * wq.x);
            row[i0] = make_float2(u.x + vt.x, u.y + vt.y);
            row[i1] = make_float2(u.x - vt.x, u.y - vt.y);
        }
        __syncthreads();
    }
    // write feat[v][x][2*ch0 + j]: per wave-store 4 fully-written 64B lines
    const float* rf = (const float*)rows;
    float* dst = feat + (size_t)v * 65536 + 2 * ch0;
#pragma unroll
    for (int k = 0; k < 8; k++) {
        int f = t + (k << 9);           // 0..4095
        int x = f >> 4;
        int j = f & 15;                 // k-slot: channel j>>1 of group, part j&1
        dst[x * 256 + j] = rf[(((j >> 1) * 257) + x) * 2 + (j & 1)];
    }
}

// ---------------- Gather: bilinear sample + Fourier integration -------------
// one wave per point; lane l owns feat[4l..4l+3]; reduce via xor-1, xor-32.
__global__ __launch_bounds__(256) void gather_kernel(const float* __restrict__ f0,
                                                     const float* __restrict__ f1,
                                                     const float* __restrict__ f2,
                                                     const float* __restrict__ pts,
                                                     float* __restrict__ out) {
    int t = threadIdx.x;
    int w = t >> 6;
    int l = t & 63;
    int n = (blockIdx.x << 2) + w;
    float in0 = pts[3 * n + 0];
    float in1 = pts[3 * n + 1];
    float in2 = pts[3 * n + 2];

    int rl = l & 7;
    float coef = (float)((1 << rl) - 1);   // 2^r - 1 for r = l&7 (lanes 0..7 span all r)
    int rbase = (l & 1) << 2;              // this lane consumes r = rbase..rbase+3
    bool top = (l >= 32);                  // k>=128 -> -sin weights
    float acc = 0.0f;

#pragma unroll
    for (int p = 0; p < 3; p++) {
        const float* fb = (p == 0) ? f0 : ((p == 1) ? f1 : f2);
        float gx = (p == 0) ? in1 : in0;
        float gy = (p == 2) ? in1 : in2;
        float sc = (p == 0) ? in0 : ((p == 1) ? in1 : in2);

        float xf = (gx + 1.0f) * 127.5f;
        float yf = (gy + 1.0f) * 127.5f;
        float x0f = floorf(xf);
        float y0f = floorf(yf);
        float wx = xf - x0f;
        float wy = yf - y0f;
        int x0 = max(0, min((int)x0f, 255));
        int y0 = max(0, min((int)y0f, 255));
        int x1 = min(x0 + 1, 255);
        int y1 = min(y0 + 1, 255);

        const float4* r00 = (const float4*)(fb + (((y0 << 8) + x0) << 8));
        const float4* r01 = (const float4*)(fb + (((y0 << 8) + x1) << 8));
        const float4* r10 = (const float4*)(fb + (((y1 << 8) + x0) << 8));
        const float4* r11 = (const float4*)(fb + (((y1 << 8) + x1) << 8));
        float4 v00 = r00[l];
        float4 v01 = r01[l];
        float4 v10 = r10[l];
        float4 v11 = r11[l];

        float w00 = (1.0f - wx) * (1.0f - wy);
        float w01 = wx * (1.0f - wy);
        float w10 = (1.0f - wx) * wy;
        float w11 = wx * wy;
        float sx = w00 * v00.x + w01 * v01.x + w10 * v10.x + w11 * v11.x;
        float sy = w00 * v00.y + w01 * v01.y + w10 * v10.y + w11 * v11.y;
        float sz = w00 * v00.z + w01 * v01.z + w10 * v10.z + w11 * v11.z;
        float sw = w00 * v00.w + w01 * v01.w + w10 * v10.w + w11 * v11.w;

        float scs = (sc + 1.0f) * 127.5f;       // s in [0,255]
        float a = scs * (1.0f / 128.0f) * coef; // theta/pi for r = l&7
        float sn, cs;
        sincospif(a, &sn, &cs);

        float c0 = __shfl(cs, rbase + 0), s0 = __shfl(sn, rbase + 0);
        float c1 = __shfl(cs, rbase + 1), s1 = __shfl(sn, rbase + 1);
        float c2 = __shfl(cs, rbase + 2), s2 = __shfl(sn, rbase + 2);
        float c3 = __shfl(cs, rbase + 3), s3 = __shfl(sn, rbase + 3);
        float w0 = top ? -s0 : c0;
        float w1 = top ? -s1 : c1;
        float w2 = top ? -s2 : c2;
        float w3 = top ? -s3 : c3;
        acc += w0 * sx + w1 * sy + w2 * sz + w3 * sw;
    }
    acc += __shfl_xor(acc, 1);
    acc += __shfl_xor(acc, 32);
    if ((l & 33) == 0) {                       // lane 2c, c = l>>1 in [0,16)
        out[((size_t)n << 4) + (l >> 1)] = acc;
    }
}

extern "C" void kernel_launch(void* const* d_in, const int* in_sizes, int n_in,
                              void* d_out, int out_size, void* d_ws, size_t ws_size,
                              hipStream_t stream) {
    const float* P[3] = {(const float*)d_in[0], (const float*)d_in[1], (const float*)d_in[2]};
    const float* pts  = (const float*)d_in[3];
    float* out = (float*)d_out;
    float* ws  = (float*)d_ws;
    // workspace layout (floats): 3 x 16.78M feat planes, then X (8.39M) = 224 MiB
    float* feats[3] = {ws, ws + 16777216, ws + 2 * (size_t)16777216};
    float2* X = (float2*)(ws + 3 * (size_t)16777216);

    for (int p = 0; p < 3; p++) {
        pass1_kernel<<<1024, 256, 0, stream>>>(P[p], X);
        pass2_kernel<<<4096, 512, 0, stream>>>(X, feats[p]);
    }
    gather_kernel<<<65536, 256, 0, stream>>>(feats[0], feats[1], feats[2], pts, out);
}

// Round 2
// 484.823 us; speedup vs baseline: 1.5023x; 1.5023x over previous
//
#include <hip/hip_runtime.h>
#include <hip/hip_bf16.h>
#include <cmath>

// PREFFFT: masked-spectrum iFFT2 (3 planes x 128ch x 256x256) + bilinear
// grid-sample at 262144 points + 8-term Fourier integration -> (N,16).
//
// feat stored channel-last bf16: feat[y][x][m], m=0..255 matching the
// reference's (2C,H,W) channel order (m = 2*ch + part). 512 B per pixel.
// Gather math: out[c] = sum_r cos(th_r)*samp[8c+r] - sin(th_r)*samp[128+8c+r],
// th_r = pi*(s+...)*coef_r/128, coef_r = 2^r-1. Lane q in [0,32) owns
// m = 8q..8q+7 (one uint4 of bf16); q<16 -> +cos weights (c=q), q>=16 ->
// -sin weights (c=q-16). Reduction: shfl_xor(16). Two points per wave.

__device__ __forceinline__ int brev8(int x) { return (int)(__brev((unsigned)x) >> 24); }

// ---------------- Pass 1: iFFT over y for each (plane, ch, x<128) column ---
// input  P[ch][y][x][2] (only y<128, x<128 nonzero), scale 1/65536
// output X[plane][ch][v][x]  complex fp32, v in [0,256), x in [0,128)
__global__ __launch_bounds__(256) void pass1_kernel(const float* __restrict__ P0,
                                                    const float* __restrict__ P1,
                                                    const float* __restrict__ P2,
                                                    float2* __restrict__ X) {
    __shared__ float2 tw[128];
    __shared__ float2 tile[256 * 17];   // [pos][col], stride 17 breaks bank conflicts

    int t = threadIdx.x;
    if (t < 128) {
        float s, c;
        sincospif((float)t * (1.0f / 128.0f), &s, &c);
        tw[t] = make_float2(c, s);      // e^{+2 pi i t/256} (inverse FFT)
    }
    int plane = blockIdx.y;
    const float* P = (plane == 0) ? P0 : ((plane == 1) ? P1 : P2);
    float2* Xp = X + (size_t)plane * 4194304;

    int b  = blockIdx.x;
    int ch = b >> 3;                    // 0..127
    int x0 = (b & 7) << 4;              // 0..112
    const float* src = P + (size_t)ch * 131072 + x0 * 2;

    const float scale = 1.0f / 65536.0f;
#pragma unroll
    for (int k = 0; k < 4; k++) {
        int i = t + (k << 8);
        int y = i >> 3;                 // 0..127
        int j = i & 7;
        float4 v = *(const float4*)(src + (size_t)y * 512 + (j << 2));
        float2 c0 = make_float2(v.x * scale, v.y * scale);
        float2 c1 = make_float2(v.z * scale, v.w * scale);
        int pos = brev8(y);             // even; writing pos and pos+1 folds stage 1
        tile[pos * 17 + 2 * j]           = c0;
        tile[(pos + 1) * 17 + 2 * j]     = c0;
        tile[pos * 17 + 2 * j + 1]       = c1;
        tile[(pos + 1) * 17 + 2 * j + 1] = c1;
    }
    __syncthreads();
    for (int s = 2; s <= 8; s++) {
        int half = 1 << (s - 1);
        int col = t & 15;
        int bb  = t >> 4;
#pragma unroll
        for (int k = 0; k < 8; k++) {
            int bf = bb + (k << 4);
            int j  = bf & (half - 1);
            int g  = bf >> (s - 1);
            int i0 = (g << s) + j;
            int i1 = i0 + half;
            float2 u = tile[i0 * 17 + col];
            float2 v = tile[i1 * 17 + col];
            float2 w = tw[j << (8 - s)];
            float2 vt = make_float2(v.x * w.x - v.y * w.y, v.x * w.y + v.y * w.x);
            tile[i0 * 17 + col] = make_float2(u.x + vt.x, u.y + vt.y);
            tile[i1 * 17 + col] = make_float2(u.x - vt.x, u.y - vt.y);
        }
        __syncthreads();
    }
    float2* dst = Xp + (size_t)ch * 32768 + x0;
#pragma unroll
    for (int k = 0; k < 16; k++) {
        int i = t + (k << 8);
        int v = i >> 4;
        int col = i & 15;
        dst[(size_t)v * 128 + col] = tile[v * 17 + col];
    }
}

// ---------------- Pass 2: iFFT over x, store feat as bf16 -------------------
// input X[plane][ch][v][x<128]; output feat[plane][v][x][m] bf16
// 16 channels per block (1024 thr, 16 waves) -> 64 B fully-written lines.
__global__ __launch_bounds__(1024) void pass2_kernel(const float2* __restrict__ X,
                                                     __hip_bfloat16* __restrict__ feat) {
    __shared__ float2 tw[128];
    __shared__ float2 rows[16 * 257];   // one 256-pt line per wave, +1 pad

    int t = threadIdx.x;
    if (t < 128) {
        float s, c;
        sincospif((float)t * (1.0f / 128.0f), &s, &c);
        tw[t] = make_float2(c, s);
    }
    int w = t >> 6;
    int l = t & 63;
    int v   = blockIdx.x & 255;
    int g   = blockIdx.x >> 8;          // 0..7 channel group
    int ch0 = g << 4;
    int ch  = ch0 + w;
    int plane = blockIdx.y;
    const float2* Xp = X + (size_t)plane * 4194304;
    __hip_bfloat16* fp = feat + (size_t)plane * 16777216;

    const float4* src = (const float4*)(Xp + ((size_t)ch * 256 + v) * 128);
    float4 d = src[l];                  // complex x=2l and x=2l+1
    float2* row = rows + w * 257;
    int p0 = brev8(2 * l);
    int p1 = brev8(2 * l + 1);
    row[p0]     = make_float2(d.x, d.y);
    row[p0 + 1] = make_float2(d.x, d.y);
    row[p1]     = make_float2(d.z, d.w);
    row[p1 + 1] = make_float2(d.z, d.w);
    __syncthreads();
    for (int s = 2; s <= 8; s++) {
        int half = 1 << (s - 1);
#pragma unroll
        for (int k = 0; k < 2; k++) {
            int bf = l + (k << 6);
            int j  = bf & (half - 1);
            int gg = bf >> (s - 1);
            int i0 = (gg << s) + j;
            int i1 = i0 + half;
            float2 u  = row[i0];
            float2 vv = row[i1];
            float2 wq = tw[j << (8 - s)];
            float2 vt = make_float2(vv.x * wq.x - vv.y * wq.y,
                                    vv.x * wq.y + vv.y * wq.x);
            row[i0] = make_float2(u.x + vt.x, u.y + vt.y);
            row[i1] = make_float2(u.x - vt.x, u.y - vt.y);
        }
        __syncthreads();
    }
    // write feat[v][x][2*ch0 + j], j in [0,32): lanes 0..31 cover 64 B line
    __hip_bfloat16* dst = fp + (size_t)v * 65536 + (ch0 << 1);
#pragma unroll
    for (int k = 0; k < 8; k++) {
        int f = t + (k << 10);          // 0..8191
        int x = f >> 5;
        int j = f & 31;                 // j = 2*jj + part
        float2 cpx = rows[(j >> 1) * 257 + x];
        float val = (j & 1) ? cpx.y : cpx.x;
        dst[x * 256 + j] = __float2bfloat16(val);
    }
}

// ---------------- Gather: bilinear sample + Fourier integration -------------
__device__ __forceinline__ float dot8(uint4 d, const float* wr) {
    float a0 = __uint_as_float(d.x << 16);
    float a1 = __uint_as_float(d.x & 0xffff0000u);
    float a2 = __uint_as_float(d.y << 16);
    float a3 = __uint_as_float(d.y & 0xffff0000u);
    float a4 = __uint_as_float(d.z << 16);
    float a5 = __uint_as_float(d.z & 0xffff0000u);
    float a6 = __uint_as_float(d.w << 16);
    float a7 = __uint_as_float(d.w & 0xffff0000u);
    return wr[0] * a0 + wr[1] * a1 + wr[2] * a2 + wr[3] * a3 +
           wr[4] * a4 + wr[5] * a5 + wr[6] * a6 + wr[7] * a7;
}

__global__ __launch_bounds__(256) void gather_kernel(const ushort* __restrict__ f0,
                                                     const ushort* __restrict__ f1,
                                                     const ushort* __restrict__ f2,
                                                     const float* __restrict__ pts,
                                                     float* __restrict__ out) {
    int t = threadIdx.x;
    int w = t >> 6;
    int l = t & 63;
    int h = l >> 5;                     // point within wave
    int q = l & 31;                     // owns m = 8q..8q+7
    int n = (blockIdx.x << 3) + (w << 1) + h;

    float in0 = pts[3 * n + 0];
    float in1 = pts[3 * n + 1];
    float in2 = pts[3 * n + 2];

    int r = q & 7;
    float coef = (float)((1 << r) - 1);
    bool iscos = (q < 16);
    float acc = 0.0f;

#pragma unroll
    for (int p = 0; p < 3; p++) {
        const ushort* fb = (p == 0) ? f0 : ((p == 1) ? f1 : f2);
        float gx = (p == 0) ? in1 : in0;
        float gy = (p == 2) ? in1 : in2;
        float sc = (p == 0) ? in0 : ((p == 1) ? in1 : in2);

        float xf = (gx + 1.0f) * 127.5f;
        float yf = (gy + 1.0f) * 127.5f;
        float x0f = floorf(xf);
        float y0f = floorf(yf);
        float wx = xf - x0f;
        float wy = yf - y0f;
        int x0 = max(0, min((int)x0f, 255));
        int y0 = max(0, min((int)y0f, 255));
        int x1 = min(x0 + 1, 255);
        int y1 = min(y0 + 1, 255);

        // per-lane trig for r=q&7, then broadcast merged cos/-sin set
        float a = (sc + 1.0f) * 0.99609375f * coef;   // theta/pi
        float sn, cs;
        sincospif(a, &sn, &cs);
        float merged = iscos ? cs : -sn;
        float wr[8];
#pragma unroll
        for (int i = 0; i < 8; i++) wr[i] = __shfl(merged, (l & 48) + i);

        uint4 d00 = *((const uint4*)(fb + ((((y0 << 8) + x0) << 8))) + q);
        uint4 d01 = *((const uint4*)(fb + ((((y0 << 8) + x1) << 8))) + q);
        uint4 d10 = *((const uint4*)(fb + ((((y1 << 8) + x0) << 8))) + q);
        uint4 d11 = *((const uint4*)(fb + ((((y1 << 8) + x1) << 8))) + q);

        float s00 = dot8(d00, wr);
        float s01 = dot8(d01, wr);
        float s10 = dot8(d10, wr);
        float s11 = dot8(d11, wr);

        float w00 = (1.0f - wx) * (1.0f - wy);
        float w01 = wx * (1.0f - wy);
        float w10 = (1.0f - wx) * wy;
        float w11 = wx * wy;
        acc += w00 * s00 + w01 * s01 + w10 * s10 + w11 * s11;
    }
    acc += __shfl_xor(acc, 16);         // combine cos-lane c and sin-lane c+16
    if (q < 16) {
        out[((size_t)n << 4) + q] = acc;
    }
}

extern "C" void kernel_launch(void* const* d_in, const int* in_sizes, int n_in,
                              void* d_out, int out_size, void* d_ws, size_t ws_size,
                              hipStream_t stream) {
    const float* P0  = (const float*)d_in[0];
    const float* P1  = (const float*)d_in[1];
    const float* P2  = (const float*)d_in[2];
    const float* pts = (const float*)d_in[3];
    float* out = (float*)d_out;

    // ws layout: feat bf16 3 x 16,777,216 elems (100.66 MB), then X fp32
    // 3 x 4,194,304 complex (100.66 MB) = 201.3 MB total.
    __hip_bfloat16* feat = (__hip_bfloat16*)d_ws;
    float2* X = (float2*)((char*)d_ws + 100663296u);

    dim3 g1(1024, 3);
    pass1_kernel<<<g1, 256, 0, stream>>>(P0, P1, P2, X);
    dim3 g2(2048, 3);
    pass2_kernel<<<g2, 1024, 0, stream>>>(X, feat);

    const ushort* fu = (const ushort*)feat;
    gather_kernel<<<32768, 256, 0, stream>>>(fu, fu + 16777216, fu + 2 * (size_t)16777216,
                                             pts, out);
}

// Round 3
// 484.319 us; speedup vs baseline: 1.5039x; 1.0010x over previous
//
#include <hip/hip_runtime.h>
#include <hip/hip_bf16.h>
#include <cmath>

// PREFFFT: masked-spectrum iFFT2 (3 planes x 128ch x 256x256) + bilinear
// grid-sample at 262144 points + 8-term Fourier integration -> (N,16).
//
// feat stored channel-last bf16: feat[y][x][m], m=0..255 (m = 2*ch + part),
// 512 B per pixel. Intermediate X (after column FFT) stored as packed-bf16
// complex. Gather: lane q in [0,32) owns m = 8q..8q+7 (one uint4 of bf16);
// q<16 -> +cos weights (out channel c=q), q>=16 -> -sin (c=q-16); weights
// via z_{r+1} = z_r^2 * z_1 recurrence (theta_r = pi*ap*(2^r-1));
// reduction shfl_xor(16). Two points per wave; all 12 corner loads hoisted
// ahead of the weight math (R2's 36-VGPR build serialized them -> latency).

__device__ __forceinline__ int brev8(int x) { return (int)(__brev((unsigned)x) >> 24); }

__device__ __forceinline__ unsigned pack_bf16(float2 v) {
    unsigned short a = __builtin_bit_cast(unsigned short, __float2bfloat16(v.x));
    unsigned short b = __builtin_bit_cast(unsigned short, __float2bfloat16(v.y));
    return (unsigned)a | ((unsigned)b << 16);
}
__device__ __forceinline__ float2 unpack_bf16(unsigned u) {
    return make_float2(__uint_as_float(u << 16), __uint_as_float(u & 0xffff0000u));
}

// ---------------- Pass 1: iFFT over y for each (plane, ch, x<128) column ---
// input  P[ch][y][x][2] (only y<128, x<128 nonzero), scale 1/65536
// output X[plane][ch][v][x]  complex packed-bf16, v in [0,256), x in [0,128)
__global__ __launch_bounds__(512) void pass1_kernel(const float* __restrict__ P0,
                                                    const float* __restrict__ P1,
                                                    const float* __restrict__ P2,
                                                    unsigned* __restrict__ X) {
    __shared__ float2 tw[128];
    __shared__ float2 tile[256 * 17];   // [pos][col], stride 17 breaks bank conflicts

    int t = threadIdx.x;
    if (t < 128) {
        float s, c;
        sincospif((float)t * (1.0f / 128.0f), &s, &c);
        tw[t] = make_float2(c, s);      // e^{+2 pi i t/256} (inverse FFT)
    }
    int plane = blockIdx.y;
    const float* P = (plane == 0) ? P0 : ((plane == 1) ? P1 : P2);
    unsigned* Xp = X + (size_t)plane * 4194304;

    int b  = blockIdx.x;
    int ch = b >> 3;                    // 0..127
    int x0 = (b & 7) << 4;              // 0..112
    const float* src = P + (size_t)ch * 131072 + x0 * 2;

    const float scale = 1.0f / 65536.0f;
#pragma unroll
    for (int k = 0; k < 2; k++) {
        int i = t + (k << 9);           // 0..1023
        int y = i >> 3;                 // 0..127
        int j = i & 7;
        float4 v = *(const float4*)(src + (size_t)y * 512 + (j << 2));
        float2 c0 = make_float2(v.x * scale, v.y * scale);
        float2 c1 = make_float2(v.z * scale, v.w * scale);
        int pos = brev8(y);             // even; writing pos and pos+1 folds stage 1
        tile[pos * 17 + 2 * j]           = c0;
        tile[(pos + 1) * 17 + 2 * j]     = c0;
        tile[pos * 17 + 2 * j + 1]       = c1;
        tile[(pos + 1) * 17 + 2 * j + 1] = c1;
    }
    __syncthreads();
    for (int s = 2; s <= 8; s++) {
        int half = 1 << (s - 1);
        int col = t & 15;
        int bb  = t >> 4;               // 0..31
#pragma unroll
        for (int k = 0; k < 4; k++) {
            int bf = bb + (k << 5);     // 0..127
            int j  = bf & (half - 1);
            int g  = bf >> (s - 1);
            int i0 = (g << s) + j;
            int i1 = i0 + half;
            float2 u = tile[i0 * 17 + col];
            float2 v = tile[i1 * 17 + col];
            float2 w = tw[j << (8 - s)];
            float2 vt = make_float2(v.x * w.x - v.y * w.y, v.x * w.y + v.y * w.x);
            tile[i0 * 17 + col] = make_float2(u.x + vt.x, u.y + vt.y);
            tile[i1 * 17 + col] = make_float2(u.x - vt.x, u.y - vt.y);
        }
        __syncthreads();
    }
    unsigned* dst = Xp + (size_t)ch * 32768 + x0;
#pragma unroll
    for (int k = 0; k < 8; k++) {
        int i = t + (k << 9);           // 0..4095
        int v = i >> 4;
        int col = i & 15;
        dst[(size_t)v * 128 + col] = pack_bf16(tile[v * 17 + col]);
    }
}

// ---------------- Pass 2: iFFT over x, store feat as bf16 -------------------
// input X[plane][ch][v][x<128] packed-bf16; output feat[plane][v][x][m] bf16
// 16 channels per block (1024 thr, 16 waves) -> 64 B fully-written lines.
__global__ __launch_bounds__(1024) void pass2_kernel(const unsigned* __restrict__ X,
                                                     __hip_bfloat16* __restrict__ feat) {
    __shared__ float2 tw[128];
    __shared__ float2 rows[16 * 257];   // one 256-pt line per wave, +1 pad

    int t = threadIdx.x;
    if (t < 128) {
        float s, c;
        sincospif((float)t * (1.0f / 128.0f), &s, &c);
        tw[t] = make_float2(c, s);
    }
    int w = t >> 6;
    int l = t & 63;
    int v   = blockIdx.x & 255;
    int g   = blockIdx.x >> 8;          // 0..7 channel group
    int ch0 = g << 4;
    int ch  = ch0 + w;
    int plane = blockIdx.y;
    const unsigned* Xp = X + (size_t)plane * 4194304;
    __hip_bfloat16* fp = feat + (size_t)plane * 16777216;

    const uint2* src = (const uint2*)(Xp + ((size_t)ch * 256 + v) * 128);
    uint2 d = src[l];                   // complex x=2l and x=2l+1
    float2 c0 = unpack_bf16(d.x);
    float2 c1 = unpack_bf16(d.y);
    float2* row = rows + w * 257;
    int p0 = brev8(2 * l);
    int p1 = brev8(2 * l + 1);
    row[p0]     = c0;
    row[p0 + 1] = c0;
    row[p1]     = c1;
    row[p1 + 1] = c1;
    __syncthreads();
    for (int s = 2; s <= 8; s++) {
        int half = 1 << (s - 1);
#pragma unroll
        for (int k = 0; k < 2; k++) {
            int bf = l + (k << 6);
            int j  = bf & (half - 1);
            int gg = bf >> (s - 1);
            int i0 = (gg << s) + j;
            int i1 = i0 + half;
            float2 u  = row[i0];
            float2 vv = row[i1];
            float2 wq = tw[j << (8 - s)];
            float2 vt = make_float2(vv.x * wq.x - vv.y * wq.y,
                                    vv.x * wq.y + vv.y * wq.x);
            row[i0] = make_float2(u.x + vt.x, u.y + vt.y);
            row[i1] = make_float2(u.x - vt.x, u.y - vt.y);
        }
        __syncthreads();
    }
    // write feat[v][x][2*ch0 + j], j in [0,32): lanes 0..31 cover 64 B line
    __hip_bfloat16* dst = fp + (size_t)v * 65536 + (ch0 << 1);
#pragma unroll
    for (int k = 0; k < 8; k++) {
        int f = t + (k << 10);          // 0..8191
        int x = f >> 5;
        int j = f & 31;                 // j = 2*jj + part
        float2 cpx = rows[(j >> 1) * 257 + x];
        float val = (j & 1) ? cpx.y : cpx.x;
        dst[x * 256 + j] = __float2bfloat16(val);
    }
}

// ---------------- Gather: bilinear sample + Fourier integration -------------
__device__ __forceinline__ float dot8(uint4 d, const float* wr) {
    float a0 = __uint_as_float(d.x << 16);
    float a1 = __uint_as_float(d.x & 0xffff0000u);
    float a2 = __uint_as_float(d.y << 16);
    float a3 = __uint_as_float(d.y & 0xffff0000u);
    float a4 = __uint_as_float(d.z << 16);
    float a5 = __uint_as_float(d.z & 0xffff0000u);
    float a6 = __uint_as_float(d.w << 16);
    float a7 = __uint_as_float(d.w & 0xffff0000u);
    return wr[0] * a0 + wr[1] * a1 + wr[2] * a2 + wr[3] * a3 +
           wr[4] * a4 + wr[5] * a5 + wr[6] * a6 + wr[7] * a7;
}

__global__ __launch_bounds__(256) void gather_kernel(const ushort* __restrict__ f0,
                                                     const ushort* __restrict__ f1,
                                                     const ushort* __restrict__ f2,
                                                     const float* __restrict__ pts,
                                                     float* __restrict__ out) {
    int t = threadIdx.x;
    int w = t >> 6;
    int l = t & 63;
    int h = l >> 5;                     // point within wave
    int q = l & 31;                     // owns m = 8q..8q+7
    int n = (blockIdx.x << 3) + (w << 1) + h;

    float in0 = pts[3 * n + 0];
    float in1 = pts[3 * n + 1];
    float in2 = pts[3 * n + 2];

    // ---- phase 1: addresses + ALL 12 loads issued up front ----
    uint4 d[3][4];
    float wxv[3], wyv[3], apv[3];
#pragma unroll
    for (int p = 0; p < 3; p++) {
        const ushort* fb = (p == 0) ? f0 : ((p == 1) ? f1 : f2);
        float gx = (p == 0) ? in1 : in0;
        float gy = (p == 2) ? in1 : in2;
        float sc = (p == 0) ? in0 : ((p == 1) ? in1 : in2);

        float xf = (gx + 1.0f) * 127.5f;
        float yf = (gy + 1.0f) * 127.5f;
        float x0f = floorf(xf);
        float y0f = floorf(yf);
        wxv[p] = xf - x0f;
        wyv[p] = yf - y0f;
        apv[p] = (sc + 1.0f) * 0.99609375f;   // theta_1 / pi
        int x0 = max(0, min((int)x0f, 255));
        int y0 = max(0, min((int)y0f, 255));
        int x1 = min(x0 + 1, 255);
        int y1 = min(y0 + 1, 255);

        d[p][0] = *((const uint4*)(fb + (((y0 << 8) + x0) << 8)) + q);
        d[p][1] = *((const uint4*)(fb + (((y0 << 8) + x1) << 8)) + q);
        d[p][2] = *((const uint4*)(fb + (((y1 << 8) + x0) << 8)) + q);
        d[p][3] = *((const uint4*)(fb + (((y1 << 8) + x1) << 8)) + q);
    }

    // ---- phase 2: weights (per-lane recurrence, no cross-lane) + dots ----
    bool iscos = (q < 16);
    float acc = 0.0f;
#pragma unroll
    for (int p = 0; p < 3; p++) {
        float sn, cs;
        sincospif(apv[p], &sn, &cs);    // z1 = e^{i pi ap}
        float wr[8];
        wr[0] = iscos ? 1.0f : 0.0f;    // r=0: theta=0
        float zr = cs, zi = sn;         // z_1
        wr[1] = iscos ? zr : -zi;
#pragma unroll
        for (int r = 2; r < 8; r++) {   // z_r = z_{r-1}^2 * z_1
            float a = zr * zr - zi * zi;
            float b = 2.0f * zr * zi;
            zr = a * cs - b * sn;
            zi = a * sn + b * cs;
            wr[r] = iscos ? zr : -zi;
        }

        float s00 = dot8(d[p][0], wr);
        float s01 = dot8(d[p][1], wr);
        float s10 = dot8(d[p][2], wr);
        float s11 = dot8(d[p][3], wr);

        float wx = wxv[p], wy = wyv[p];
        float w00 = (1.0f - wx) * (1.0f - wy);
        float w01 = wx * (1.0f - wy);
        float w10 = (1.0f - wx) * wy;
        float w11 = wx * wy;
        acc += w00 * s00 + w01 * s01 + w10 * s10 + w11 * s11;
    }
    acc += __shfl_xor(acc, 16);         // combine cos-lane c and sin-lane c+16
    if (q < 16) {
        out[((size_t)n << 4) + q] = acc;
    }
}

extern "C" void kernel_launch(void* const* d_in, const int* in_sizes, int n_in,
                              void* d_out, int out_size, void* d_ws, size_t ws_size,
                              hipStream_t stream) {
    const float* P0  = (const float*)d_in[0];
    const float* P1  = (const float*)d_in[1];
    const float* P2  = (const float*)d_in[2];
    const float* pts = (const float*)d_in[3];
    float* out = (float*)d_out;

    // ws layout: feat bf16 3 x 16,777,216 elems (100.66 MB), then X packed-bf16
    // 3 x 4,194,304 complex (50.33 MB) = 151 MB total.
    __hip_bfloat16* feat = (__hip_bfloat16*)d_ws;
    unsigned* X = (unsigned*)((char*)d_ws + 100663296u);

    dim3 g1(1024, 3);
    pass1_kernel<<<g1, 512, 0, stream>>>(P0, P1, P2, X);
    dim3 g2(2048, 3);
    pass2_kernel<<<g2, 1024, 0, stream>>>(X, feat);

    const ushort* fu = (const ushort*)feat;
    gather_kernel<<<32768, 256, 0, stream>>>(fu, fu + 16777216, fu + 2 * (size_t)16777216,
                                             pts, out);
}

// Round 4
// 416.253 us; speedup vs baseline: 1.7498x; 1.1635x over previous
//
#include <hip/hip_runtime.h>
#include <hip/hip_bf16.h>
#include <cmath>

// PREFFFT: masked-spectrum iFFT2 (3 planes x 128ch x 256x256) + bilinear
// grid-sample at 262144 points + 8-term Fourier integration -> (N,16).
//
// R4: gather is locality-sorted. Points are counting-sorted per plane by
// 16x16-pixel tile (256 bins); sorted gather works one plane per block
// (grid.y), so the active feat window (~2MB) stays L2-resident instead of
// thrashing the 3.5 TB/s TCC-miss path (R2/R3: 757MB FETCH @ 217us).
// Per-plane partials -> combine kernel (deterministic). FFT stage loops
// are #pragma unroll'd so butterfly index math is compile-time.

#define NPTS 262144

__device__ __forceinline__ int brev8(int x) { return (int)(__brev((unsigned)x) >> 24); }

__device__ __forceinline__ unsigned pack_bf16(float2 v) {
    unsigned short a = __builtin_bit_cast(unsigned short, __float2bfloat16(v.x));
    unsigned short b = __builtin_bit_cast(unsigned short, __float2bfloat16(v.y));
    return (unsigned)a | ((unsigned)b << 16);
}
__device__ __forceinline__ float2 unpack_bf16(unsigned u) {
    return make_float2(__uint_as_float(u << 16), __uint_as_float(u & 0xffff0000u));
}

// plane coordinate mapping (matches reference):
// p=0: gx=in1 gy=in2 s=in0 | p=1: gx=in0 gy=in2 s=in1 | p=2: gx=in0 gy=in1 s=in2
__device__ __forceinline__ void plane_coords(int p, float in0, float in1, float in2,
                                             float& gx, float& gy, float& sc) {
    gx = (p == 0) ? in1 : in0;
    gy = (p == 2) ? in1 : in2;
    sc = (p == 0) ? in0 : ((p == 1) ? in1 : in2);
}

// ---------------- Pass 1: iFFT over y for each (plane, ch, x<128) column ---
__global__ __launch_bounds__(512) void pass1_kernel(const float* __restrict__ P0,
                                                    const float* __restrict__ P1,
                                                    const float* __restrict__ P2,
                                                    unsigned* __restrict__ X) {
    __shared__ float2 tw[128];
    __shared__ float2 tile[256 * 17];

    int t = threadIdx.x;
    if (t < 128) {
        float s, c;
        sincospif((float)t * (1.0f / 128.0f), &s, &c);
        tw[t] = make_float2(c, s);
    }
    int plane = blockIdx.y;
    const float* P = (plane == 0) ? P0 : ((plane == 1) ? P1 : P2);
    unsigned* Xp = X + (size_t)plane * 4194304;

    int b  = blockIdx.x;
    int ch = b >> 3;
    int x0 = (b & 7) << 4;
    const float* src = P + (size_t)ch * 131072 + x0 * 2;

    const float scale = 1.0f / 65536.0f;
#pragma unroll
    for (int k = 0; k < 2; k++) {
        int i = t + (k << 9);
        int y = i >> 3;
        int j = i & 7;
        float4 v = *(const float4*)(src + (size_t)y * 512 + (j << 2));
        float2 c0 = make_float2(v.x * scale, v.y * scale);
        float2 c1 = make_float2(v.z * scale, v.w * scale);
        int pos = brev8(y);
        tile[pos * 17 + 2 * j]           = c0;
        tile[(pos + 1) * 17 + 2 * j]     = c0;
        tile[pos * 17 + 2 * j + 1]       = c1;
        tile[(pos + 1) * 17 + 2 * j + 1] = c1;
    }
    __syncthreads();
#pragma unroll
    for (int s = 2; s <= 8; s++) {
        int half = 1 << (s - 1);
        int col = t & 15;
        int bb  = t >> 4;
#pragma unroll
        for (int k = 0; k < 4; k++) {
            int bf = bb + (k << 5);
            int j  = bf & (half - 1);
            int g  = bf >> (s - 1);
            int i0 = (g << s) + j;
            int i1 = i0 + half;
            float2 u = tile[i0 * 17 + col];
            float2 v = tile[i1 * 17 + col];
            float2 w = tw[j << (8 - s)];
            float2 vt = make_float2(v.x * w.x - v.y * w.y, v.x * w.y + v.y * w.x);
            tile[i0 * 17 + col] = make_float2(u.x + vt.x, u.y + vt.y);
            tile[i1 * 17 + col] = make_float2(u.x - vt.x, u.y - vt.y);
        }
        __syncthreads();
    }
    unsigned* dst = Xp + (size_t)ch * 32768 + x0;
#pragma unroll
    for (int k = 0; k < 8; k++) {
        int i = t + (k << 9);
        int v = i >> 4;
        int col = i & 15;
        dst[(size_t)v * 128 + col] = pack_bf16(tile[v * 17 + col]);
    }
}

// ---------------- Pass 2: iFFT over x, store feat as bf16 -------------------
__global__ __launch_bounds__(1024) void pass2_kernel(const unsigned* __restrict__ X,
                                                     __hip_bfloat16* __restrict__ feat) {
    __shared__ float2 tw[128];
    __shared__ float2 rows[16 * 257];

    int t = threadIdx.x;
    if (t < 128) {
        float s, c;
        sincospif((float)t * (1.0f / 128.0f), &s, &c);
        tw[t] = make_float2(c, s);
    }
    int w = t >> 6;
    int l = t & 63;
    int v   = blockIdx.x & 255;
    int g   = blockIdx.x >> 8;
    int ch0 = g << 4;
    int ch  = ch0 + w;
    int plane = blockIdx.y;
    const unsigned* Xp = X + (size_t)plane * 4194304;
    __hip_bfloat16* fp = feat + (size_t)plane * 16777216;

    const uint2* src = (const uint2*)(Xp + ((size_t)ch * 256 + v) * 128);
    uint2 d = src[l];
    float2 c0 = unpack_bf16(d.x);
    float2 c1 = unpack_bf16(d.y);
    float2* row = rows + w * 257;
    int p0 = brev8(2 * l);
    int p1 = brev8(2 * l + 1);
    row[p0]     = c0;
    row[p0 + 1] = c0;
    row[p1]     = c1;
    row[p1 + 1] = c1;
    __syncthreads();
#pragma unroll
    for (int s = 2; s <= 8; s++) {
        int half = 1 << (s - 1);
#pragma unroll
        for (int k = 0; k < 2; k++) {
            int bf = l + (k << 6);
            int j  = bf & (half - 1);
            int gg = bf >> (s - 1);
            int i0 = (gg << s) + j;
            int i1 = i0 + half;
            float2 u  = row[i0];
            float2 vv = row[i1];
            float2 wq = tw[j << (8 - s)];
            float2 vt = make_float2(vv.x * wq.x - vv.y * wq.y,
                                    vv.x * wq.y + vv.y * wq.x);
            row[i0] = make_float2(u.x + vt.x, u.y + vt.y);
            row[i1] = make_float2(u.x - vt.x, u.y - vt.y);
        }
        __syncthreads();
    }
    __hip_bfloat16* dst = fp + (size_t)v * 65536 + (ch0 << 1);
#pragma unroll
    for (int k = 0; k < 8; k++) {
        int f = t + (k << 10);
        int x = f >> 5;
        int j = f & 31;
        float2 cpx = rows[(j >> 1) * 257 + x];
        float val = (j & 1) ? cpx.y : cpx.x;
        dst[x * 256 + j] = __float2bfloat16(val);
    }
}

// ---------------- Sort: histogram / scan / scatter --------------------------
__device__ __forceinline__ int tile_key(int p, float in0, float in1, float in2) {
    float gx, gy, sc;
    plane_coords(p, in0, in1, in2, gx, gy, sc);
    float xf = (gx + 1.0f) * 127.5f;
    float yf = (gy + 1.0f) * 127.5f;
    int x0 = max(0, min((int)floorf(xf), 255));
    int y0 = max(0, min((int)floorf(yf), 255));
    return (y0 & 0xF0) | (x0 >> 4);
}

__global__ __launch_bounds__(1024) void hist_kernel(const float* __restrict__ pts,
                                                    unsigned* __restrict__ hist) {
    __shared__ unsigned hb[256];
    int t = threadIdx.x;
    int p = blockIdx.y;
    int n = (blockIdx.x << 10) + t;
    if (t < 256) hb[t] = 0;
    __syncthreads();
    float in0 = pts[3 * n + 0], in1 = pts[3 * n + 1], in2 = pts[3 * n + 2];
    int key = tile_key(p, in0, in1, in2);
    atomicAdd(&hb[key], 1u);
    __syncthreads();
    if (t < 256 && hb[t]) atomicAdd(&hist[(p << 8) + t], hb[t]);
}

__global__ __launch_bounds__(256) void scan_kernel(const unsigned* __restrict__ hist,
                                                   unsigned* __restrict__ cursor) {
    __shared__ unsigned s[256];
    int t = threadIdx.x;
    for (int p = 0; p < 3; p++) {
        unsigned v = hist[(p << 8) + t];
        s[t] = v;
        __syncthreads();
#pragma unroll
        for (int d = 1; d < 256; d <<= 1) {
            unsigned add = (t >= d) ? s[t - d] : 0u;
            __syncthreads();
            s[t] += add;
            __syncthreads();
        }
        cursor[(p << 8) + t] = s[t] - v;   // exclusive prefix
        __syncthreads();
    }
}

__global__ __launch_bounds__(1024) void scatter_kernel(const float* __restrict__ pts,
                                                       unsigned* __restrict__ cursor,
                                                       int* __restrict__ order) {
    __shared__ unsigned cnt[256];
    __shared__ unsigned base[256];
    int t = threadIdx.x;
    int p = blockIdx.y;
    int n = (blockIdx.x << 10) + t;
    if (t < 256) cnt[t] = 0;
    __syncthreads();
    float in0 = pts[3 * n + 0], in1 = pts[3 * n + 1], in2 = pts[3 * n + 2];
    int key = tile_key(p, in0, in1, in2);
    unsigned rank = atomicAdd(&cnt[key], 1u);
    __syncthreads();
    if (t < 256 && cnt[t]) base[t] = atomicAdd(&cursor[(p << 8) + t], cnt[t]);
    __syncthreads();
    order[p * NPTS + base[key] + rank] = n;
}

// ---------------- Gather (sorted, one plane per block) ----------------------
__device__ __forceinline__ float dot8(uint4 d, const float* wr) {
    float a0 = __uint_as_float(d.x << 16);
    float a1 = __uint_as_float(d.x & 0xffff0000u);
    float a2 = __uint_as_float(d.y << 16);
    float a3 = __uint_as_float(d.y & 0xffff0000u);
    float a4 = __uint_as_float(d.z << 16);
    float a5 = __uint_as_float(d.z & 0xffff0000u);
    float a6 = __uint_as_float(d.w << 16);
    float a7 = __uint_as_float(d.w & 0xffff0000u);
    return wr[0] * a0 + wr[1] * a1 + wr[2] * a2 + wr[3] * a3 +
           wr[4] * a4 + wr[5] * a5 + wr[6] * a6 + wr[7] * a7;
}

__global__ __launch_bounds__(256) void gather_kernel(const ushort* __restrict__ feat,
                                                     const int* __restrict__ order,
                                                     const float* __restrict__ pts,
                                                     float* __restrict__ partial) {
    int t = threadIdx.x;
    int w = t >> 6;
    int l = t & 63;
    int h = l >> 5;                     // point within wave
    int q = l & 31;                     // owns m = 8q..8q+7
    int p = blockIdx.y;
    const ushort* fb = feat + (size_t)p * 16777216;

    int idx = (blockIdx.x << 3) + (w << 1) + h;
    int n = order[p * NPTS + idx];
    float in0 = pts[3 * n + 0], in1 = pts[3 * n + 1], in2 = pts[3 * n + 2];
    float gx, gy, sc;
    plane_coords(p, in0, in1, in2, gx, gy, sc);

    float xf = (gx + 1.0f) * 127.5f;
    float yf = (gy + 1.0f) * 127.5f;
    float x0f = floorf(xf);
    float y0f = floorf(yf);
    float wx = xf - x0f;
    float wy = yf - y0f;
    int x0 = max(0, min((int)x0f, 255));
    int y0 = max(0, min((int)y0f, 255));
    int x1 = min(x0 + 1, 255);
    int y1 = min(y0 + 1, 255);

    uint4 d00 = *((const uint4*)(fb + (((y0 << 8) + x0) << 8)) + q);
    uint4 d01 = *((const uint4*)(fb + (((y0 << 8) + x1) << 8)) + q);
    uint4 d10 = *((const uint4*)(fb + (((y1 << 8) + x0) << 8)) + q);
    uint4 d11 = *((const uint4*)(fb + (((y1 << 8) + x1) << 8)) + q);

    // weights: lane with r=q&7 computes theta_r; broadcast cos (q<16 src) or
    // -sin (q>=16 src) to all lanes of this point via shfl from (l&48)+i.
    float coef = (float)((1 << (q & 7)) - 1);
    float a = (sc + 1.0f) * 0.99609375f * coef;   // theta/pi
    float sn, cs;
    sincospif(a, &sn, &cs);
    float merged = (q < 16) ? cs : -sn;
    float wr[8];
#pragma unroll
    for (int i = 0; i < 8; i++) wr[i] = __shfl(merged, (l & 48) + i);

    float s00 = dot8(d00, wr);
    float s01 = dot8(d01, wr);
    float s10 = dot8(d10, wr);
    float s11 = dot8(d11, wr);

    float w00 = (1.0f - wx) * (1.0f - wy);
    float w01 = wx * (1.0f - wy);
    float w10 = (1.0f - wx) * wy;
    float w11 = wx * wy;
    float acc = w00 * s00 + w01 * s01 + w10 * s10 + w11 * s11;

    acc += __shfl_xor(acc, 16);         // cos-lane c + sin-lane c+16
    if (q < 16) {
        partial[(((size_t)p * NPTS + n) << 4) + q] = acc;
    }
}

__global__ __launch_bounds__(256) void combine_kernel(const float4* __restrict__ pa,
                                                      float4* __restrict__ out) {
    int i = (blockIdx.x << 8) + threadIdx.x;     // 0..1048575
    float4 a = pa[i];
    float4 b = pa[i + 1048576];
    float4 c = pa[i + 2097152];
    out[i] = make_float4(a.x + b.x + c.x, a.y + b.y + c.y,
                         a.z + b.z + c.z, a.w + b.w + c.w);
}

extern "C" void kernel_launch(void* const* d_in, const int* in_sizes, int n_in,
                              void* d_out, int out_size, void* d_ws, size_t ws_size,
                              hipStream_t stream) {
    const float* P0  = (const float*)d_in[0];
    const float* P1  = (const float*)d_in[1];
    const float* P2  = (const float*)d_in[2];
    const float* pts = (const float*)d_in[3];
    float* out = (float*)d_out;
    char* ws = (char*)d_ws;

    // ws layout (bytes):
    __hip_bfloat16* feat = (__hip_bfloat16*)ws;                    // 100,663,296
    unsigned* X          = (unsigned*)(ws + 100663296u);           //  50,331,648
    float*    partial    = (float*)(ws + 150994944u);              //  50,331,648
    int*      order      = (int*)(ws + 201326592u);                //   3,145,728
    unsigned* hist       = (unsigned*)(ws + 204472320u);           //       3,072
    unsigned* cursor     = (unsigned*)(ws + 204475392u);           //       3,072

    hipMemsetAsync(hist, 0, 3072, stream);

    dim3 g1(1024, 3);
    pass1_kernel<<<g1, 512, 0, stream>>>(P0, P1, P2, X);
    dim3 g2(2048, 3);
    pass2_kernel<<<g2, 1024, 0, stream>>>(X, feat);

    dim3 gs(256, 3);
    hist_kernel<<<gs, 1024, 0, stream>>>(pts, hist);
    scan_kernel<<<1, 256, 0, stream>>>(hist, cursor);
    scatter_kernel<<<gs, 1024, 0, stream>>>(pts, cursor, order);

    dim3 gg(32768, 3);
    gather_kernel<<<gg, 256, 0, stream>>>((const ushort*)feat, order, pts, partial);
    combine_kernel<<<4096, 256, 0, stream>>>((const float4*)partial, (float4*)out);
}

// Round 5
// 395.736 us; speedup vs baseline: 1.8405x; 1.0518x over previous
//
#include <hip/hip_runtime.h>
#include <hip/hip_bf16.h>
#include <cmath>

// PREFFFT: masked-spectrum iFFT2 (3 planes x 128ch x 256x256) + bilinear
// grid-sample at 262144 points + 8-term Fourier integration -> (N,16).
//
// R5: (1) FFT passes restructured so butterfly stages are wave-private
// (pass1: wave owns a column pair; pass2: wave owns its row) -> 2 barriers
// per block instead of 7-9 (barrier-drain was the stall; ~1 TB/s eff).
// (2) gather: XCD-chunk swizzle of the sorted order (each XCD gets one
// contiguous ~4.6MB tile window ~= its L2) to kill the 8x cross-XCD feat
// replication (R4: 391MB FETCH vs 100MB unique); scatter emits a float4
// (gx,gy,s,n) table so gather has zero random point reads; bilerp in
// packed fp32 (v_pk_fma_f32) to cut VALU (R4 gather VALUBusy ~109%).

#define NPTS 262144

typedef float vf2 __attribute__((ext_vector_type(2)));

__device__ __forceinline__ int brev8(int x) { return (int)(__brev((unsigned)x) >> 24); }

__device__ __forceinline__ unsigned pack_bf16(float2 v) {
    unsigned short a = __builtin_bit_cast(unsigned short, __float2bfloat16(v.x));
    unsigned short b = __builtin_bit_cast(unsigned short, __float2bfloat16(v.y));
    return (unsigned)a | ((unsigned)b << 16);
}
__device__ __forceinline__ float2 unpack_bf16(unsigned u) {
    return make_float2(__uint_as_float(u << 16), __uint_as_float(u & 0xffff0000u));
}
__device__ __forceinline__ vf2 up2(unsigned u) {
    vf2 r; r.x = __uint_as_float(u << 16); r.y = __uint_as_float(u & 0xffff0000u);
    return r;
}

// plane coordinate mapping (matches reference):
// p=0: gx=in1 gy=in2 s=in0 | p=1: gx=in0 gy=in2 s=in1 | p=2: gx=in0 gy=in1 s=in2
__device__ __forceinline__ void plane_coords(int p, float in0, float in1, float in2,
                                             float& gx, float& gy, float& sc) {
    gx = (p == 0) ? in1 : in0;
    gy = (p == 2) ? in1 : in2;
    sc = (p == 0) ? in0 : ((p == 1) ? in1 : in2);
}

// ---------------- Pass 1: iFFT over y for each (plane, ch, x<128) column ---
// Cooperative load/store; butterfly stages wave-private (wave w: cols 2w,2w+1).
__global__ __launch_bounds__(512) void pass1_kernel(const float* __restrict__ P0,
                                                    const float* __restrict__ P1,
                                                    const float* __restrict__ P2,
                                                    unsigned* __restrict__ X) {
    __shared__ float2 tw[128];
    __shared__ float2 tile[256 * 17];

    int t = threadIdx.x;
    if (t < 128) {
        float s, c;
        sincospif((float)t * (1.0f / 128.0f), &s, &c);
        tw[t] = make_float2(c, s);
    }
    int plane = blockIdx.y;
    const float* P = (plane == 0) ? P0 : ((plane == 1) ? P1 : P2);
    unsigned* Xp = X + (size_t)plane * 4194304;

    int b  = blockIdx.x;
    int ch = b >> 3;
    int x0 = (b & 7) << 4;
    const float* src = P + (size_t)ch * 131072 + x0 * 2;

    const float scale = 1.0f / 65536.0f;
#pragma unroll
    for (int k = 0; k < 2; k++) {
        int i = t + (k << 9);
        int y = i >> 3;
        int j = i & 7;
        float4 v = *(const float4*)(src + (size_t)y * 512 + (j << 2));
        float2 c0 = make_float2(v.x * scale, v.y * scale);
        float2 c1 = make_float2(v.z * scale, v.w * scale);
        int pos = brev8(y);             // even; writing pos and pos+1 folds stage 1
        tile[pos * 17 + 2 * j]           = c0;
        tile[(pos + 1) * 17 + 2 * j]     = c0;
        tile[pos * 17 + 2 * j + 1]       = c1;
        tile[(pos + 1) * 17 + 2 * j + 1] = c1;
    }
    __syncthreads();

    int w = t >> 6, l = t & 63;
    int col = (w << 1) + (l & 1);       // wave-private column
    int bb  = l >> 1;                   // 0..31
#pragma unroll
    for (int s = 2; s <= 8; s++) {
        int half = 1 << (s - 1);
#pragma unroll
        for (int k = 0; k < 4; k++) {
            int bf = bb + (k << 5);     // 0..127
            int j  = bf & (half - 1);
            int g  = bf >> (s - 1);
            int i0 = (g << s) + j;
            int i1 = i0 + half;
            float2 u = tile[i0 * 17 + col];
            float2 v = tile[i1 * 17 + col];
            float2 wq = tw[j << (8 - s)];
            float2 vt = make_float2(v.x * wq.x - v.y * wq.y, v.x * wq.y + v.y * wq.x);
            tile[i0 * 17 + col] = make_float2(u.x + vt.x, u.y + vt.y);
            tile[i1 * 17 + col] = make_float2(u.x - vt.x, u.y - vt.y);
        }
        // wave-private: no barrier between stages
    }
    __syncthreads();

    unsigned* dst = Xp + (size_t)ch * 32768 + x0;
#pragma unroll
    for (int k = 0; k < 8; k++) {
        int i = t + (k << 9);
        int v = i >> 4;
        int c = i & 15;
        dst[(size_t)v * 128 + c] = pack_bf16(tile[v * 17 + c]);
    }
}

// ---------------- Pass 2: iFFT over x, store feat as bf16 -------------------
// Rows are wave-private: no per-stage barriers.
__global__ __launch_bounds__(1024) void pass2_kernel(const unsigned* __restrict__ X,
                                                     __hip_bfloat16* __restrict__ feat) {
    __shared__ float2 tw[128];
    __shared__ float2 rows[16 * 257];

    int t = threadIdx.x;
    if (t < 128) {
        float s, c;
        sincospif((float)t * (1.0f / 128.0f), &s, &c);
        tw[t] = make_float2(c, s);
    }
    int w = t >> 6;
    int l = t & 63;
    int v   = blockIdx.x & 255;
    int g   = blockIdx.x >> 8;
    int ch0 = g << 4;
    int ch  = ch0 + w;
    int plane = blockIdx.y;
    const unsigned* Xp = X + (size_t)plane * 4194304;
    __hip_bfloat16* fp = feat + (size_t)plane * 16777216;

    const uint2* src = (const uint2*)(Xp + ((size_t)ch * 256 + v) * 128);
    uint2 d = src[l];
    float2 c0 = unpack_bf16(d.x);
    float2 c1 = unpack_bf16(d.y);
    float2* row = rows + w * 257;
    int p0 = brev8(2 * l);
    int p1 = brev8(2 * l + 1);
    row[p0]     = c0;
    row[p0 + 1] = c0;
    row[p1]     = c1;
    row[p1 + 1] = c1;
    __syncthreads();                    // covers tw init (rows are wave-private)
#pragma unroll
    for (int s = 2; s <= 8; s++) {
        int half = 1 << (s - 1);
#pragma unroll
        for (int k = 0; k < 2; k++) {
            int bf = l + (k << 6);
            int j  = bf & (half - 1);
            int gg = bf >> (s - 1);
            int i0 = (gg << s) + j;
            int i1 = i0 + half;
            float2 u  = row[i0];
            float2 vv = row[i1];
            float2 wq = tw[j << (8 - s)];
            float2 vt = make_float2(vv.x * wq.x - vv.y * wq.y,
                                    vv.x * wq.y + vv.y * wq.x);
            row[i0] = make_float2(u.x + vt.x, u.y + vt.y);
            row[i1] = make_float2(u.x - vt.x, u.y - vt.y);
        }
        // wave-private: no barrier
    }
    __syncthreads();                    // epilogue reads other waves' rows
    __hip_bfloat16* dst = fp + (size_t)v * 65536 + (ch0 << 1);
#pragma unroll
    for (int k = 0; k < 8; k++) {
        int f = t + (k << 10);
        int x = f >> 5;
        int j = f & 31;
        float2 cpx = rows[(j >> 1) * 257 + x];
        float val = (j & 1) ? cpx.y : cpx.x;
        dst[x * 256 + j] = __float2bfloat16(val);
    }
}

// ---------------- Sort: histogram / scan / scatter --------------------------
__device__ __forceinline__ int tile_key(float gx, float gy) {
    float xf = (gx + 1.0f) * 127.5f;
    float yf = (gy + 1.0f) * 127.5f;
    int x0 = max(0, min((int)floorf(xf), 255));
    int y0 = max(0, min((int)floorf(yf), 255));
    return (y0 & 0xF0) | (x0 >> 4);
}

__global__ __launch_bounds__(1024) void hist_kernel(const float* __restrict__ pts,
                                                    unsigned* __restrict__ hist) {
    __shared__ unsigned hb[256];
    int t = threadIdx.x;
    int p = blockIdx.y;
    int n = (blockIdx.x << 10) + t;
    if (t < 256) hb[t] = 0;
    __syncthreads();
    float in0 = pts[3 * n + 0], in1 = pts[3 * n + 1], in2 = pts[3 * n + 2];
    float gx, gy, sc;
    plane_coords(p, in0, in1, in2, gx, gy, sc);
    atomicAdd(&hb[tile_key(gx, gy)], 1u);
    __syncthreads();
    if (t < 256 && hb[t]) atomicAdd(&hist[(p << 8) + t], hb[t]);
}

__global__ __launch_bounds__(256) void scan_kernel(const unsigned* __restrict__ hist,
                                                   unsigned* __restrict__ cursor) {
    __shared__ unsigned s[256];
    int t = threadIdx.x;
    for (int p = 0; p < 3; p++) {
        unsigned v = hist[(p << 8) + t];
        s[t] = v;
        __syncthreads();
#pragma unroll
        for (int d = 1; d < 256; d <<= 1) {
            unsigned add = (t >= d) ? s[t - d] : 0u;
            __syncthreads();
            s[t] += add;
            __syncthreads();
        }
        cursor[(p << 8) + t] = s[t] - v;   // exclusive prefix
        __syncthreads();
    }
}

// writes per-plane sorted point table: (gx, gy, s, bitcast(n))
__global__ __launch_bounds__(1024) void scatter_kernel(const float* __restrict__ pts,
                                                       unsigned* __restrict__ cursor,
                                                       float4* __restrict__ psort) {
    __shared__ unsigned cnt[256];
    __shared__ unsigned base[256];
    int t = threadIdx.x;
    int p = blockIdx.y;
    int n = (blockIdx.x << 10) + t;
    if (t < 256) cnt[t] = 0;
    __syncthreads();
    float in0 = pts[3 * n + 0], in1 = pts[3 * n + 1], in2 = pts[3 * n + 2];
    float gx, gy, sc;
    plane_coords(p, in0, in1, in2, gx, gy, sc);
    int key = tile_key(gx, gy);
    unsigned rank = atomicAdd(&cnt[key], 1u);
    __syncthreads();
    if (t < 256 && cnt[t]) base[t] = atomicAdd(&cursor[(p << 8) + t], cnt[t]);
    __syncthreads();
    psort[p * NPTS + base[key] + rank] = make_float4(gx, gy, sc, __int_as_float(n));
}

// ---------------- Gather (sorted, XCD-chunk swizzled) -----------------------
__global__ __launch_bounds__(256) void gather_kernel(const ushort* __restrict__ feat,
                                                     const float4* __restrict__ psort,
                                                     float* __restrict__ partial) {
    int t = threadIdx.x;
    int w = t >> 6;
    int l = t & 63;
    int h = l >> 5;                     // point within wave
    int q = l & 31;                     // owns m = 8q..8q+7
    int p = blockIdx.y;
    const ushort* fb = feat + (size_t)p * 16777216;

    // XCD swizzle: dispatch b -> XCD b%8; give each XCD one contiguous chunk
    int b  = blockIdx.x;                        // 0..32767
    int lb = ((b & 7) << 12) | (b >> 3);        // logical sorted block
    int idx = (lb << 3) + (w << 1) + h;
    float4 pt = psort[p * NPTS + idx];
    float gx = pt.x, gy = pt.y, sc = pt.z;
    int n = __float_as_int(pt.w);

    float xf = (gx + 1.0f) * 127.5f;
    float yf = (gy + 1.0f) * 127.5f;
    float x0f = floorf(xf);
    float y0f = floorf(yf);
    float wx = xf - x0f;
    float wy = yf - y0f;
    int x0 = max(0, min((int)x0f, 255));
    int y0 = max(0, min((int)y0f, 255));
    int dx = (x0 < 255) ? 256 : 0;      // +1 pixel in x = 256 ushorts
    int dy = (y0 < 255) ? 65536 : 0;    // +1 pixel in y = 65536 ushorts

    const ushort* bp = fb + (((y0 << 8) + x0) << 8) + (q << 3);
    uint4 d00 = *(const uint4*)bp;
    uint4 d01 = *(const uint4*)(bp + dx);
    uint4 d10 = *(const uint4*)(bp + dy);
    uint4 d11 = *(const uint4*)(bp + dx + dy);

    // weights: lane with r=q&7 computes theta_r; broadcast merged cos/-sin
    float coef = (float)((1 << (q & 7)) - 1);
    float a = (sc + 1.0f) * 0.99609375f * coef;   // theta/pi
    float sn, cs;
    sincospif(a, &sn, &cs);
    float merged = (q < 16) ? cs : -sn;
    float wr0 = __shfl(merged, (l & 48) + 0);
    float wr1 = __shfl(merged, (l & 48) + 1);
    float wr2 = __shfl(merged, (l & 48) + 2);
    float wr3 = __shfl(merged, (l & 48) + 3);
    float wr4 = __shfl(merged, (l & 48) + 4);
    float wr5 = __shfl(merged, (l & 48) + 5);
    float wr6 = __shfl(merged, (l & 48) + 6);
    float wr7 = __shfl(merged, (l & 48) + 7);

    float w00 = (1.0f - wx) * (1.0f - wy);
    float w01 = wx * (1.0f - wy);
    float w10 = (1.0f - wx) * wy;
    float w11 = wx * wy;

    // packed-fp32 bilerp then dot with the broadcast weights
    vf2 b0 = w00 * up2(d00.x) + w01 * up2(d01.x) + w10 * up2(d10.x) + w11 * up2(d11.x);
    vf2 b1 = w00 * up2(d00.y) + w01 * up2(d01.y) + w10 * up2(d10.y) + w11 * up2(d11.y);
    vf2 b2 = w00 * up2(d00.z) + w01 * up2(d01.z) + w10 * up2(d10.z) + w11 * up2(d11.z);
    vf2 b3 = w00 * up2(d00.w) + w01 * up2(d01.w) + w10 * up2(d10.w) + w11 * up2(d11.w);

    vf2 wa; wa.x = wr0; wa.y = wr1;
    vf2 wb; wb.x = wr2; wb.y = wr3;
    vf2 wc; wc.x = wr4; wc.y = wr5;
    vf2 wd; wd.x = wr6; wd.y = wr7;
    vf2 acc2 = b0 * wa + b1 * wb + b2 * wc + b3 * wd;
    float acc = acc2.x + acc2.y;

    acc += __shfl_xor(acc, 16);         // cos-lane c + sin-lane c+16
    if (q < 16) {
        partial[(((size_t)p * NPTS + n) << 4) + q] = acc;
    }
}

__global__ __launch_bounds__(256) void combine_kernel(const float4* __restrict__ pa,
                                                      float4* __restrict__ out) {
    int i = (blockIdx.x << 8) + threadIdx.x;     // 0..1048575
    float4 a = pa[i];
    float4 b = pa[i + 1048576];
    float4 c = pa[i + 2097152];
    out[i] = make_float4(a.x + b.x + c.x, a.y + b.y + c.y,
                         a.z + b.z + c.z, a.w + b.w + c.w);
}

extern "C" void kernel_launch(void* const* d_in, const int* in_sizes, int n_in,
                              void* d_out, int out_size, void* d_ws, size_t ws_size,
                              hipStream_t stream) {
    const float* P0  = (const float*)d_in[0];
    const float* P1  = (const float*)d_in[1];
    const float* P2  = (const float*)d_in[2];
    const float* pts = (const float*)d_in[3];
    float* out = (float*)d_out;
    char* ws = (char*)d_ws;

    // ws layout (bytes):
    __hip_bfloat16* feat = (__hip_bfloat16*)ws;                    // 100,663,296
    unsigned* X          = (unsigned*)(ws + 100663296u);           //  50,331,648
    float*    partial    = (float*)(ws + 150994944u);              //  50,331,648
    float4*   psort      = (float4*)(ws + 201326592u);             //  12,582,912
    unsigned* hist       = (unsigned*)(ws + 213909504u);           //       3,072
    unsigned* cursor     = (unsigned*)(ws + 213912576u);           //       3,072

    hipMemsetAsync(hist, 0, 3072, stream);

    dim3 g1(1024, 3);
    pass1_kernel<<<g1, 512, 0, stream>>>(P0, P1, P2, X);
    dim3 g2(2048, 3);
    pass2_kernel<<<g2, 1024, 0, stream>>>(X, feat);

    dim3 gs(256, 3);
    hist_kernel<<<gs, 1024, 0, stream>>>(pts, hist);
    scan_kernel<<<1, 256, 0, stream>>>(hist, cursor);
    scatter_kernel<<<gs, 1024, 0, stream>>>(pts, cursor, psort);

    dim3 gg(32768, 3);
    gather_kernel<<<gg, 256, 0, stream>>>((const ushort*)feat, psort, partial);
    combine_kernel<<<4096, 256, 0, stream>>>((const float4*)partial, (float4*)out);
}